// Round 14
// baseline (390.733 us; speedup 1.0000x reference)
//
// v14 — fused_mlp rewrite: LDS-minimal. A- and W-fragments read directly from
// global (W is L2-resident + broadcast; A read once); only T1 (32KB, XOR-swizzled)
// lives in LDS. Fixes v13's 2M bank conflicts + 16% occupancy (78KB LDS).
// Everything else identical to v13.
#include <hip/hip_runtime.h>

#define N_NODES 50000
#define N_EDGES 800000
#define D_IN 96
#define D_HID 256
#define N_GRAPHS 64

#define SCAN_NB ((N_NODES + 255) / 256)

typedef __attribute__((ext_vector_type(8))) short bf16x8;
typedef __attribute__((ext_vector_type(4))) float f32x4;

__device__ __forceinline__ unsigned short f2bf(float f) {
    union { float f; unsigned int u; } v; v.f = f;
    unsigned int r = (v.u + 0x7FFFu + ((v.u >> 16) & 1u)) >> 16;  // RNE
    return (unsigned short)r;
}
__device__ __forceinline__ float bfLo(unsigned int u) {
    union { unsigned int u; float f; } v; v.u = u << 16; return v.f;
}
__device__ __forceinline__ float bfHi(unsigned int u) {
    union { unsigned int u; float f; } v; v.u = u & 0xFFFF0000u; return v.f;
}
__device__ __forceinline__ unsigned int packbf(float a, float b) {
    return (unsigned int)f2bf(a) | ((unsigned int)f2bf(b) << 16);
}

// ---------------- CSR build ----------------
__global__ void k_count(const int* __restrict__ dst, int* __restrict__ deg, int E) {
    int e = blockIdx.x * blockDim.x + threadIdx.x;
    if (e < E) atomicAdd(&deg[dst[e]], 1);
}

__global__ __launch_bounds__(256) void k_scan1(const int* __restrict__ deg,
                                               int* __restrict__ bsum, int n) {
    __shared__ int red[256];
    int tid = threadIdx.x;
    int i = blockIdx.x * 256 + tid;
    red[tid] = (i < n) ? deg[i] : 0;
    __syncthreads();
    for (int off = 128; off > 0; off >>= 1) {
        if (tid < off) red[tid] += red[tid + off];
        __syncthreads();
    }
    if (tid == 0) bsum[blockIdx.x] = red[0];
}

__global__ __launch_bounds__(256) void k_scan2(int* __restrict__ bsum, int nb) {
    __shared__ int s[256];
    int tid = threadIdx.x;
    int v = (tid < nb) ? bsum[tid] : 0;
    s[tid] = v;
    __syncthreads();
    for (int off = 1; off < 256; off <<= 1) {
        int t = (tid >= off) ? s[tid - off] : 0;
        __syncthreads();
        s[tid] += t;
        __syncthreads();
    }
    if (tid < nb) bsum[tid] = s[tid] - v;
}

__global__ __launch_bounds__(256) void k_scan3(const int* __restrict__ deg,
                                               const int* __restrict__ bsum,
                                               int* __restrict__ rp,
                                               int* __restrict__ wp, int n) {
    __shared__ int s[256];
    int tid = threadIdx.x;
    int i = blockIdx.x * 256 + tid;
    int v = (i < n) ? deg[i] : 0;
    s[tid] = v;
    __syncthreads();
    for (int off = 1; off < 256; off <<= 1) {
        int t = (tid >= off) ? s[tid - off] : 0;
        __syncthreads();
        s[tid] += t;
        __syncthreads();
    }
    if (i < n) {
        int excl = s[tid] - v + bsum[blockIdx.x];
        rp[i] = excl;
        wp[i] = excl;
    }
    if (blockIdx.x == 0 && tid == 0) rp[n] = N_EDGES;
}

__global__ void k_scatter(const int* __restrict__ src, const int* __restrict__ dst,
                          int* __restrict__ wp, int* __restrict__ csr, int E) {
    int e = blockIdx.x * blockDim.x + threadIdx.x;
    if (e < E) {
        int p = atomicAdd(&wp[dst[e]], 1);
        csr[p] = src[e];
    }
}

// ---------------- x f32 -> bf16 ----------------
__global__ __launch_bounds__(256) void k_x2bf(const float* __restrict__ x,
                                              unsigned short* __restrict__ xb, int n4) {
    int i = blockIdx.x * 256 + threadIdx.x;
    if (i >= n4) return;
    float4 v = ((const float4*)x)[i];
    ((uint2*)xb)[i] = make_uint2(packbf(v.x, v.y), packbf(v.z, v.w));
}

#define ACCUM(acc, v)                                    \
    do {                                                 \
        acc[0] += bfLo((v).x); acc[1] += bfHi((v).x);    \
        acc[2] += bfLo((v).y); acc[3] += bfHi((v).y);    \
        acc[4] += bfLo((v).z); acc[5] += bfHi((v).z);    \
        acc[6] += bfLo((v).w); acc[7] += bfHi((v).w);    \
    } while (0)

// ---------------- aggregation (unchanged from v12) ----------------
__global__ __launch_bounds__(256) void k_agg96b(const unsigned short* __restrict__ xb,
                                                const int* __restrict__ rp,
                                                const int* __restrict__ csr,
                                                unsigned short* __restrict__ h0, int n) {
    int wid = blockIdx.x * 4 + (threadIdx.x >> 6);
    if (wid >= n) return;
    int lane = threadIdx.x & 63;
    int grp = lane / 12;
    int sub = lane % 12;
    int s = rp[wid], e = rp[wid + 1];
    const uint4* xp = (const uint4*)xb;
    float a[8] = {0.f, 0.f, 0.f, 0.f, 0.f, 0.f, 0.f, 0.f};
    float b[8] = {0.f, 0.f, 0.f, 0.f, 0.f, 0.f, 0.f, 0.f};
    if (lane < 48) {
        int j = s + grp;
        for (; j + 4 < e; j += 8) {
            int sc0 = csr[j];
            int sc1 = csr[j + 4];
            uint4 v0 = xp[(size_t)sc0 * 12 + sub];
            uint4 v1 = xp[(size_t)sc1 * 12 + sub];
            ACCUM(a, v0);
            ACCUM(b, v1);
        }
        if (j < e) {
            int sc0 = csr[j];
            uint4 v0 = xp[(size_t)sc0 * 12 + sub];
            ACCUM(a, v0);
        }
    }
#pragma unroll
    for (int i = 0; i < 8; i++) a[i] += b[i];
#pragma unroll
    for (int i = 0; i < 8; i++) a[i] += __shfl(a[i], lane + 24, 64);
#pragma unroll
    for (int i = 0; i < 8; i++) a[i] += __shfl(a[i], lane + 12, 64);
    if (lane < 12) {
        uint4 v = xp[(size_t)wid * 12 + sub];
        ACCUM(a, v);
        uint4 o;
        o.x = packbf(a[0], a[1]); o.y = packbf(a[2], a[3]);
        o.z = packbf(a[4], a[5]); o.w = packbf(a[6], a[7]);
        ((uint4*)h0)[(size_t)wid * 12 + sub] = o;
    }
}

__global__ __launch_bounds__(256) void k_agg256b(const unsigned short* __restrict__ h,
                                                 const int* __restrict__ rp,
                                                 const int* __restrict__ csr,
                                                 unsigned short* __restrict__ outb, int n) {
    int wid = blockIdx.x * 4 + (threadIdx.x >> 6);
    if (wid >= n) return;
    int lane = threadIdx.x & 63;
    int half = lane >> 5;
    int sub = lane & 31;
    int s = rp[wid], e = rp[wid + 1];
    const uint4* hp = (const uint4*)h;
    float a[8] = {0.f, 0.f, 0.f, 0.f, 0.f, 0.f, 0.f, 0.f};
    float b[8] = {0.f, 0.f, 0.f, 0.f, 0.f, 0.f, 0.f, 0.f};
    int j = s + half;
    for (; j + 2 < e; j += 4) {
        int sc0 = csr[j];
        int sc1 = csr[j + 2];
        uint4 v0 = hp[(size_t)sc0 * 32 + sub];
        uint4 v1 = hp[(size_t)sc1 * 32 + sub];
        ACCUM(a, v0);
        ACCUM(b, v1);
    }
    if (j < e) {
        int sc0 = csr[j];
        uint4 v0 = hp[(size_t)sc0 * 32 + sub];
        ACCUM(a, v0);
    }
#pragma unroll
    for (int i = 0; i < 8; i++) a[i] += b[i];
#pragma unroll
    for (int i = 0; i < 8; i++) a[i] += __shfl(a[i], sub + 32, 64);
    if (half == 0) {
        uint4 v = hp[(size_t)wid * 32 + sub];
        ACCUM(a, v);
        uint4 o;
        o.x = packbf(a[0], a[1]); o.y = packbf(a[2], a[3]);
        o.z = packbf(a[4], a[5]); o.w = packbf(a[6], a[7]);
        ((uint4*)outb)[(size_t)wid * 32 + sub] = o;
    }
}

// ---------------- weight transpose + bf16: W[K][256] -> Wt[256][K] ----------------
__global__ __launch_bounds__(256) void k_wt(const float* __restrict__ W,
                                            unsigned short* __restrict__ Wt, int K) {
    int idx = blockIdx.x * 256 + threadIdx.x;
    if (idx >= K * 256) return;
    int k = idx >> 8;
    int n = idx & 255;
    Wt[(size_t)n * K + k] = f2bf(W[idx]);
}

// ---------------- fused MLP v2: LDS-minimal ----------------
// C = act2(relu(A@W1+b1)@W2+b2). Block 64 rows x 256 cols, 4 waves (2x2).
// GEMM1: A,W1 frags direct from global (no LDS, no barriers).
// T1 (64x256 bf16, 32KB LDS, XOR-swizzled 16B units) holds relu output.
// GEMM2: A frags from T1, W2 frags direct from global (L2-broadcast).
template <int K1, bool RELU2>
__global__ __launch_bounds__(256) void fused_mlp(const unsigned short* __restrict__ A,
                                                 const unsigned short* __restrict__ W1t,
                                                 const float* __restrict__ bias1,
                                                 const unsigned short* __restrict__ W2t,
                                                 const float* __restrict__ bias2,
                                                 unsigned short* __restrict__ C, int M) {
    __shared__ unsigned short T1[64 * 256];  // row*256 + swizzled col
    const int tid = threadIdx.x;
    const int lane = tid & 63;
    const int wid = tid >> 6;
    const int wm = wid >> 1;  // row half
    const int wn = wid & 1;   // col half
    const int row0 = blockIdx.x * 64;
    const int l15 = lane & 15;
    const int l4 = lane >> 4;  // 0..3

    const bf16x8 ZV = {0, 0, 0, 0, 0, 0, 0, 0};
    f32x4 acc[2][8];
#pragma unroll
    for (int f = 0; f < 2; f++)
#pragma unroll
        for (int g = 0; g < 8; g++) acc[f][g] = (f32x4){0.f, 0.f, 0.f, 0.f};

    // ---- GEMM1: acc += A @ W1t^T, fragments direct from global ----
    const int r0 = row0 + wm * 32 + l15;          // f=0 row
    const int n0 = wn * 128 + l15;                // g=0 col
#pragma unroll 2
    for (int ks = 0; ks < K1 / 32; ks++) {
        int k = ks * 32 + l4 * 8;
        bf16x8 af[2], bfr[8];
#pragma unroll
        for (int f = 0; f < 2; f++) {
            int r = r0 + f * 16;
            af[f] = (r < M) ? *(const bf16x8*)&A[(size_t)r * K1 + k] : ZV;
        }
#pragma unroll
        for (int g = 0; g < 8; g++)
            bfr[g] = *(const bf16x8*)&W1t[(size_t)(n0 + g * 16) * K1 + k];
#pragma unroll
        for (int f = 0; f < 2; f++)
#pragma unroll
            for (int g = 0; g < 8; g++)
                acc[f][g] = __builtin_amdgcn_mfma_f32_16x16x32_bf16(
                    af[f], bfr[g], acc[f][g], 0, 0, 0);
    }

    // ---- t1 = relu(acc + b1) -> T1 (swizzled), reset acc ----
#pragma unroll
    for (int g = 0; g < 8; g++) {
        int col = wn * 128 + g * 16 + l15;
        float bb = bias1[col];
#pragma unroll
        for (int f = 0; f < 2; f++) {
#pragma unroll
            for (int r = 0; r < 4; r++) {
                int row = wm * 32 + f * 16 + l4 * 4 + r;
                float v = fmaxf(acc[f][g][r] + bb, 0.f);
                int sw = (((col >> 3) ^ (row & 7)) << 3) | (col & 7);
                T1[row * 256 + sw] = f2bf(v);
            }
        }
    }
#pragma unroll
    for (int f = 0; f < 2; f++)
#pragma unroll
        for (int g = 0; g < 8; g++) acc[f][g] = (f32x4){0.f, 0.f, 0.f, 0.f};
    __syncthreads();

    // ---- GEMM2: acc += T1 @ W2t^T ----
#pragma unroll 2
    for (int ks = 0; ks < 8; ks++) {
        int k = ks * 32 + l4 * 8;  // multiple of 8
        bf16x8 af[2], bfr[8];
#pragma unroll
        for (int f = 0; f < 2; f++) {
            int row = wm * 32 + f * 16 + l15;
            af[f] = *(const bf16x8*)&T1[row * 256 + (((k >> 3) ^ (row & 7)) << 3)];
        }
#pragma unroll
        for (int g = 0; g < 8; g++)
            bfr[g] = *(const bf16x8*)&W2t[(size_t)(n0 + g * 16) * 256 + k];
#pragma unroll
        for (int f = 0; f < 2; f++)
#pragma unroll
            for (int g = 0; g < 8; g++)
                acc[f][g] = __builtin_amdgcn_mfma_f32_16x16x32_bf16(
                    af[f], bfr[g], acc[f][g], 0, 0, 0);
    }

    // ---- epilogue: bias2 (+relu), bf16 store ----
#pragma unroll
    for (int g = 0; g < 8; g++) {
        int n = wn * 128 + g * 16 + l15;
        float bb = bias2[n];
#pragma unroll
        for (int f = 0; f < 2; f++) {
#pragma unroll
            for (int r = 0; r < 4; r++) {
                int m = row0 + wm * 32 + f * 16 + l4 * 4 + r;
                if (m < M) {
                    float v = acc[f][g][r] + bb;
                    if (RELU2) v = fmaxf(v, 0.f);
                    C[(size_t)m * 256 + n] = f2bf(v);
                }
            }
        }
    }
}

// ---------------- pooling (two-stage, bf16 input) ----------------
#define POOL_ROWS 64
__global__ __launch_bounds__(256) void k_pool_partial(const unsigned short* __restrict__ h,
                                                      const int* __restrict__ batch,
                                                      float* __restrict__ psum, int n) {
    int r0 = blockIdx.x * POOL_ROWS;
    int r1 = r0 + POOL_ROWS;
    if (r1 > n) r1 = n;
    if (r0 >= r1) return;
    int c = threadIdx.x;
    float acc = 0.f;
    int g = batch[r0];
    for (int r = r0; r < r1; r++) {
        int gr = batch[r];
        if (gr != g) {
            atomicAdd(&psum[g * 256 + c], acc);
            acc = 0.f;
            g = gr;
        }
        acc += bfLo((unsigned int)h[(size_t)r * 256 + c]);
    }
    atomicAdd(&psum[g * 256 + c], acc);
}

__device__ __forceinline__ int lower_bound_i(const int* __restrict__ a, int n, int v) {
    int lo = 0, hi = n;
    while (lo < hi) {
        int mid = (lo + hi) >> 1;
        if (a[mid] < v) lo = mid + 1; else hi = mid;
    }
    return lo;
}

__global__ __launch_bounds__(128) void k_head(const float* __restrict__ psum,
                                              const int* __restrict__ batch,
                                              const float* __restrict__ Wl,
                                              const float* __restrict__ bl,
                                              float* __restrict__ out, int n) {
    int tid = threadIdx.x;
    int g = tid >> 1, o = tid & 1;
    int s = lower_bound_i(batch, n, g);
    int e = lower_bound_i(batch, n, g + 1);
    float inv = 1.0f / (float)((e - s) > 1 ? (e - s) : 1);
    float sum = bl[o];
    for (int k = 0; k < 256; k++)
        sum = fmaf(psum[g * 256 + k] * inv, Wl[k * 2 + o], sum);
    out[g * 2 + o] = sum;
}

// ---------------- launch ----------------
extern "C" void kernel_launch(void* const* d_in, const int* in_sizes, int n_in,
                              void* d_out, int out_size, void* d_ws, size_t ws_size,
                              hipStream_t stream) {
    const float* x = (const float*)d_in[0];
    const int* ei = (const int*)d_in[1];
    const int* batch = (const int*)d_in[2];
    const float* W1 = (const float*)d_in[3];
    const float* b1 = (const float*)d_in[4];
    const float* W2 = (const float*)d_in[5];
    const float* b2 = (const float*)d_in[6];
    const float* V1 = (const float*)d_in[7];
    const float* c1 = (const float*)d_in[8];
    const float* V2 = (const float*)d_in[9];
    const float* c2 = (const float*)d_in[10];
    const float* Wl = (const float*)d_in[11];
    const float* bl = (const float*)d_in[12];
    float* out = (float*)d_out;

    const int* srcp = ei;
    const int* dstp = ei + N_EDGES;

    char* ws = (char*)d_ws;
    size_t off = 0;
    auto alloc = [&](size_t bytes) {
        size_t o = off;
        off = (off + bytes + 255) & ~(size_t)255;
        return o;
    };
    size_t o_deg = alloc(sizeof(int) * (N_NODES + 1));
    size_t o_rp = alloc(sizeof(int) * (N_NODES + 1));
    size_t o_wp = alloc(sizeof(int) * (N_NODES + 1));
    size_t o_bsum = alloc(sizeof(int) * SCAN_NB);
    size_t o_csr = alloc(sizeof(int) * N_EDGES);
    size_t o_B1 = alloc(sizeof(unsigned short) * (size_t)N_NODES * D_HID);
    size_t o_B2 = alloc(sizeof(unsigned short) * (size_t)N_NODES * D_HID);
    size_t o_pool = alloc(sizeof(float) * N_GRAPHS * D_HID);
    size_t o_wt1 = alloc(sizeof(unsigned short) * D_IN * D_HID);
    size_t o_wt2 = alloc(sizeof(unsigned short) * D_HID * D_HID);
    size_t o_wv1 = alloc(sizeof(unsigned short) * D_HID * D_HID);
    size_t o_wv2 = alloc(sizeof(unsigned short) * D_HID * D_HID);
    (void)ws_size;

    int* deg = (int*)(ws + o_deg);
    int* rp = (int*)(ws + o_rp);
    int* wp = (int*)(ws + o_wp);
    int* bsum = (int*)(ws + o_bsum);
    int* csr = (int*)(ws + o_csr);
    unsigned short* B1 = (unsigned short*)(ws + o_B1);
    unsigned short* B2 = (unsigned short*)(ws + o_B2);
    float* psum = (float*)(ws + o_pool);
    unsigned short* wt1 = (unsigned short*)(ws + o_wt1);
    unsigned short* wt2 = (unsigned short*)(ws + o_wt2);
    unsigned short* wv1 = (unsigned short*)(ws + o_wv1);
    unsigned short* wv2 = (unsigned short*)(ws + o_wv2);

    hipMemsetAsync(deg, 0, sizeof(int) * (N_NODES + 1), stream);
    hipMemsetAsync(psum, 0, sizeof(float) * N_GRAPHS * D_HID, stream);

    k_wt<<<D_IN, 256, 0, stream>>>(W1, wt1, D_IN);
    k_wt<<<D_HID, 256, 0, stream>>>(W2, wt2, D_HID);
    k_wt<<<D_HID, 256, 0, stream>>>(V1, wv1, D_HID);
    k_wt<<<D_HID, 256, 0, stream>>>(V2, wv2, D_HID);

    k_count<<<(N_EDGES + 255) / 256, 256, 0, stream>>>(dstp, deg, N_EDGES);
    k_scan1<<<SCAN_NB, 256, 0, stream>>>(deg, bsum, N_NODES);
    k_scan2<<<1, 256, 0, stream>>>(bsum, SCAN_NB);
    k_scan3<<<SCAN_NB, 256, 0, stream>>>(deg, bsum, rp, wp, N_NODES);
    k_scatter<<<(N_EDGES + 255) / 256, 256, 0, stream>>>(srcp, dstp, wp, csr, N_EDGES);

    // x -> bf16 (into B1)
    k_x2bf<<<(N_NODES * D_IN / 4 + 255) / 256, 256, 0, stream>>>(x, B1, N_NODES * D_IN / 4);

    int mlpgrid = (N_NODES + 63) / 64;

    // layer 1: h0 = xb + agg(xb) -> B2; h1 = relu(relu(h0@W1+b1)@W2+b2) -> B1
    k_agg96b<<<(N_NODES + 3) / 4, 256, 0, stream>>>(B1, rp, csr, B2, N_NODES);
    fused_mlp<96, true><<<mlpgrid, 256, 0, stream>>>(B2, wt1, b1, wt2, b2, B1, N_NODES);

    // layer 2: g2 = h1 + agg(h1) -> B2; h2 = relu(g2@V1+c1)@V2+c2 -> B1 (bf16)
    k_agg256b<<<(N_NODES + 3) / 4, 256, 0, stream>>>(B1, rp, csr, B2, N_NODES);
    fused_mlp<256, false><<<mlpgrid, 256, 0, stream>>>(B2, wv1, c1, wv2, c2, B1, N_NODES);

    // pool + head
    k_pool_partial<<<(N_NODES + POOL_ROWS - 1) / POOL_ROWS, 256, 0, stream>>>(
        B1, batch, psum, N_NODES);
    k_head<<<1, 128, 0, stream>>>(psum, batch, Wl, bl, out, N_NODES);
}

// Round 16
// 371.235 us; speedup vs baseline: 1.0525x; 1.0525x over previous
//
// v16 — identical to v15 (fusion revert + dst-range-partitioned scatter);
// resubmission after UnresponsiveContainer infra failure.
#include <hip/hip_runtime.h>

#define N_NODES 50000
#define N_EDGES 800000
#define D_IN 96
#define D_HID 256
#define N_GRAPHS 64

#define SCAN_NB ((N_NODES + 255) / 256)

typedef __attribute__((ext_vector_type(8))) short bf16x8;
typedef __attribute__((ext_vector_type(4))) float f32x4;

__device__ __forceinline__ unsigned short f2bf(float f) {
    union { float f; unsigned int u; } v; v.f = f;
    unsigned int r = (v.u + 0x7FFFu + ((v.u >> 16) & 1u)) >> 16;  // RNE
    return (unsigned short)r;
}
__device__ __forceinline__ float bfLo(unsigned int u) {
    union { unsigned int u; float f; } v; v.u = u << 16; return v.f;
}
__device__ __forceinline__ float bfHi(unsigned int u) {
    union { unsigned int u; float f; } v; v.u = u & 0xFFFF0000u; return v.f;
}
__device__ __forceinline__ unsigned int packbf(float a, float b) {
    return (unsigned int)f2bf(a) | ((unsigned int)f2bf(b) << 16);
}

// ---------------- CSR build ----------------
__global__ void k_count(const int* __restrict__ dst, int* __restrict__ deg, int E) {
    int e = blockIdx.x * blockDim.x + threadIdx.x;
    if (e < E) atomicAdd(&deg[dst[e]], 1);
}

__global__ __launch_bounds__(256) void k_scan1(const int* __restrict__ deg,
                                               int* __restrict__ bsum, int n) {
    __shared__ int red[256];
    int tid = threadIdx.x;
    int i = blockIdx.x * 256 + tid;
    red[tid] = (i < n) ? deg[i] : 0;
    __syncthreads();
    for (int off = 128; off > 0; off >>= 1) {
        if (tid < off) red[tid] += red[tid + off];
        __syncthreads();
    }
    if (tid == 0) bsum[blockIdx.x] = red[0];
}

__global__ __launch_bounds__(256) void k_scan2(int* __restrict__ bsum, int nb) {
    __shared__ int s[256];
    int tid = threadIdx.x;
    int v = (tid < nb) ? bsum[tid] : 0;
    s[tid] = v;
    __syncthreads();
    for (int off = 1; off < 256; off <<= 1) {
        int t = (tid >= off) ? s[tid - off] : 0;
        __syncthreads();
        s[tid] += t;
        __syncthreads();
    }
    if (tid < nb) bsum[tid] = s[tid] - v;
}

__global__ __launch_bounds__(256) void k_scan3(const int* __restrict__ deg,
                                               const int* __restrict__ bsum,
                                               int* __restrict__ rp,
                                               int* __restrict__ wp, int n) {
    __shared__ int s[256];
    int tid = threadIdx.x;
    int i = blockIdx.x * 256 + tid;
    int v = (i < n) ? deg[i] : 0;
    s[tid] = v;
    __syncthreads();
    for (int off = 1; off < 256; off <<= 1) {
        int t = (tid >= off) ? s[tid - off] : 0;
        __syncthreads();
        s[tid] += t;
        __syncthreads();
    }
    if (i < n) {
        int excl = s[tid] - v + bsum[blockIdx.x];
        rp[i] = excl;
        wp[i] = excl;
    }
    if (blockIdx.x == 0 && tid == 0) rp[n] = N_EDGES;
}

// dst-range-partitioned scatter: range = bid&7 (XCD round-robin), 32 chunks/range.
// Each range's csr writes land in one compact dst-ordered region -> no cross-XCD
// line bouncing. Costs 8x re-read of dst (coalesced).
__global__ __launch_bounds__(256) void k_scatter2(const int* __restrict__ src,
                                                  const int* __restrict__ dst,
                                                  int* __restrict__ wp,
                                                  int* __restrict__ csr, int E) {
    int range = blockIdx.x & 7;
    int chunk = blockIdx.x >> 3;  // 0..31
    int lo = range * (N_NODES / 8);
    int hi = (range == 7) ? N_NODES : lo + (N_NODES / 8);
    int per = (E + 31) / 32;
    int s = chunk * per;
    int e = s + per;
    if (e > E) e = E;
    for (int i = s + threadIdx.x; i < e; i += 256) {
        int d = dst[i];
        if (d >= lo && d < hi) {
            int p = atomicAdd(&wp[d], 1);
            csr[p] = src[i];
        }
    }
}

// ---------------- x f32 -> bf16 ----------------
__global__ __launch_bounds__(256) void k_x2bf(const float* __restrict__ x,
                                              unsigned short* __restrict__ xb, int n4) {
    int i = blockIdx.x * 256 + threadIdx.x;
    if (i >= n4) return;
    float4 v = ((const float4*)x)[i];
    ((uint2*)xb)[i] = make_uint2(packbf(v.x, v.y), packbf(v.z, v.w));
}

#define ACCUM(acc, v)                                    \
    do {                                                 \
        acc[0] += bfLo((v).x); acc[1] += bfHi((v).x);    \
        acc[2] += bfLo((v).y); acc[3] += bfHi((v).y);    \
        acc[4] += bfLo((v).z); acc[5] += bfHi((v).z);    \
        acc[6] += bfLo((v).w); acc[7] += bfHi((v).w);    \
    } while (0)

// ---------------- aggregation (2x-unrolled, from v12) ----------------
__global__ __launch_bounds__(256) void k_agg96b(const unsigned short* __restrict__ xb,
                                                const int* __restrict__ rp,
                                                const int* __restrict__ csr,
                                                unsigned short* __restrict__ h0, int n) {
    int wid = blockIdx.x * 4 + (threadIdx.x >> 6);
    if (wid >= n) return;
    int lane = threadIdx.x & 63;
    int grp = lane / 12;
    int sub = lane % 12;
    int s = rp[wid], e = rp[wid + 1];
    const uint4* xp = (const uint4*)xb;
    float a[8] = {0.f, 0.f, 0.f, 0.f, 0.f, 0.f, 0.f, 0.f};
    float b[8] = {0.f, 0.f, 0.f, 0.f, 0.f, 0.f, 0.f, 0.f};
    if (lane < 48) {
        int j = s + grp;
        for (; j + 4 < e; j += 8) {
            int sc0 = csr[j];
            int sc1 = csr[j + 4];
            uint4 v0 = xp[(size_t)sc0 * 12 + sub];
            uint4 v1 = xp[(size_t)sc1 * 12 + sub];
            ACCUM(a, v0);
            ACCUM(b, v1);
        }
        if (j < e) {
            int sc0 = csr[j];
            uint4 v0 = xp[(size_t)sc0 * 12 + sub];
            ACCUM(a, v0);
        }
    }
#pragma unroll
    for (int i = 0; i < 8; i++) a[i] += b[i];
#pragma unroll
    for (int i = 0; i < 8; i++) a[i] += __shfl(a[i], lane + 24, 64);
#pragma unroll
    for (int i = 0; i < 8; i++) a[i] += __shfl(a[i], lane + 12, 64);
    if (lane < 12) {
        uint4 v = xp[(size_t)wid * 12 + sub];
        ACCUM(a, v);
        uint4 o;
        o.x = packbf(a[0], a[1]); o.y = packbf(a[2], a[3]);
        o.z = packbf(a[4], a[5]); o.w = packbf(a[6], a[7]);
        ((uint4*)h0)[(size_t)wid * 12 + sub] = o;
    }
}

__global__ __launch_bounds__(256) void k_agg256b(const unsigned short* __restrict__ h,
                                                 const int* __restrict__ rp,
                                                 const int* __restrict__ csr,
                                                 unsigned short* __restrict__ outb, int n) {
    int wid = blockIdx.x * 4 + (threadIdx.x >> 6);
    if (wid >= n) return;
    int lane = threadIdx.x & 63;
    int half = lane >> 5;
    int sub = lane & 31;
    int s = rp[wid], e = rp[wid + 1];
    const uint4* hp = (const uint4*)h;
    float a[8] = {0.f, 0.f, 0.f, 0.f, 0.f, 0.f, 0.f, 0.f};
    float b[8] = {0.f, 0.f, 0.f, 0.f, 0.f, 0.f, 0.f, 0.f};
    int j = s + half;
    for (; j + 2 < e; j += 4) {
        int sc0 = csr[j];
        int sc1 = csr[j + 2];
        uint4 v0 = hp[(size_t)sc0 * 32 + sub];
        uint4 v1 = hp[(size_t)sc1 * 32 + sub];
        ACCUM(a, v0);
        ACCUM(b, v1);
    }
    if (j < e) {
        int sc0 = csr[j];
        uint4 v0 = hp[(size_t)sc0 * 32 + sub];
        ACCUM(a, v0);
    }
#pragma unroll
    for (int i = 0; i < 8; i++) a[i] += b[i];
#pragma unroll
    for (int i = 0; i < 8; i++) a[i] += __shfl(a[i], sub + 32, 64);
    if (half == 0) {
        uint4 v = hp[(size_t)wid * 32 + sub];
        ACCUM(a, v);
        uint4 o;
        o.x = packbf(a[0], a[1]); o.y = packbf(a[2], a[3]);
        o.z = packbf(a[4], a[5]); o.w = packbf(a[6], a[7]);
        ((uint4*)outb)[(size_t)wid * 32 + sub] = o;
    }
}

// ---------------- weight transpose + bf16: W[K][256] -> Wt[256][K] ----------------
__global__ __launch_bounds__(256) void k_wt(const float* __restrict__ W,
                                            unsigned short* __restrict__ Wt, int K) {
    int idx = blockIdx.x * 256 + threadIdx.x;
    if (idx >= K * 256) return;
    int k = idx >> 8;
    int n = idx & 255;
    Wt[(size_t)n * K + k] = f2bf(W[idx]);
}

// ---------------- MFMA bf16 GEMM (v12's proven version) ----------------
template <int K, bool RELU, bool OUTBF>
__global__ __launch_bounds__(256) void gemm_mfma(const unsigned short* __restrict__ A,
                                                 const unsigned short* __restrict__ Wt,
                                                 const float* __restrict__ bias,
                                                 void* __restrict__ Cv, int M) {
    constexpr int BM = 64, BN = 128, BK = 64;
    __shared__ unsigned short As[BM][BK + 8];
    __shared__ unsigned short Bs[BN][BK + 8];
    const int tid = threadIdx.x;
    const int lane = tid & 63;
    const int wid = tid >> 6;
    const int wm = wid >> 1;
    const int wn = wid & 1;
    const int row0 = blockIdx.x * BM;
    const int col0 = blockIdx.y * BN;

    f32x4 acc[2][4];
#pragma unroll
    for (int f = 0; f < 2; f++)
#pragma unroll
        for (int g = 0; g < 4; g++) acc[f][g] = (f32x4){0.f, 0.f, 0.f, 0.f};

    for (int kt = 0; kt < K; kt += BK) {
        __syncthreads();
        {
            int m = tid >> 2;
            int kc = (tid & 3) * 16;
            int gr = row0 + m;
            uint4 w0 = make_uint4(0u, 0u, 0u, 0u), w1 = w0;
            int k = kt + kc;
            if (gr < M && k < K) {
                w0 = *(const uint4*)&A[(size_t)gr * K + k];
                if (k + 8 < K) w1 = *(const uint4*)&A[(size_t)gr * K + k + 8];
            }
            uint4* dst = (uint4*)&As[m][kc];
            dst[0] = w0; dst[1] = w1;
        }
        {
            int n = tid >> 1;
            int kc = (tid & 1) * 32;
            uint4 w[4];
#pragma unroll
            for (int i = 0; i < 4; i++) {
                int k = kt + kc + i * 8;
                if (k < K)
                    w[i] = *(const uint4*)&Wt[(size_t)(col0 + n) * K + k];
                else
                    w[i] = make_uint4(0u, 0u, 0u, 0u);
            }
            uint4* dst = (uint4*)&Bs[n][kc];
#pragma unroll
            for (int i = 0; i < 4; i++) dst[i] = w[i];
        }
        __syncthreads();
#pragma unroll
        for (int ks = 0; ks < 2; ks++) {
            int ko = ks * 32 + (lane >> 4) * 8;
            bf16x8 af[2], bfr[4];
#pragma unroll
            for (int f = 0; f < 2; f++)
                af[f] = *(const bf16x8*)&As[wm * 32 + f * 16 + (lane & 15)][ko];
#pragma unroll
            for (int g = 0; g < 4; g++)
                bfr[g] = *(const bf16x8*)&Bs[wn * 64 + g * 16 + (lane & 15)][ko];
#pragma unroll
            for (int f = 0; f < 2; f++)
#pragma unroll
                for (int g = 0; g < 4; g++)
                    acc[f][g] = __builtin_amdgcn_mfma_f32_16x16x32_bf16(
                        af[f], bfr[g], acc[f][g], 0, 0, 0);
        }
    }

#pragma unroll
    for (int g = 0; g < 4; g++) {
        int n = col0 + wn * 64 + g * 16 + (lane & 15);
        float bb = bias[n];
#pragma unroll
        for (int f = 0; f < 2; f++) {
#pragma unroll
            for (int r = 0; r < 4; r++) {
                int m = row0 + wm * 32 + f * 16 + (lane >> 4) * 4 + r;
                if (m < M) {
                    float v = acc[f][g][r] + bb;
                    if (RELU) v = fmaxf(v, 0.f);
                    if (OUTBF)
                        ((unsigned short*)Cv)[(size_t)m * 256 + n] = f2bf(v);
                    else
                        ((float*)Cv)[(size_t)m * 256 + n] = v;
                }
            }
        }
    }
}

// ---------------- pooling (two-stage, bf16 input) ----------------
#define POOL_ROWS 64
__global__ __launch_bounds__(256) void k_pool_partial(const unsigned short* __restrict__ h,
                                                      const int* __restrict__ batch,
                                                      float* __restrict__ psum, int n) {
    int r0 = blockIdx.x * POOL_ROWS;
    int r1 = r0 + POOL_ROWS;
    if (r1 > n) r1 = n;
    if (r0 >= r1) return;
    int c = threadIdx.x;
    float acc = 0.f;
    int g = batch[r0];
    for (int r = r0; r < r1; r++) {
        int gr = batch[r];
        if (gr != g) {
            atomicAdd(&psum[g * 256 + c], acc);
            acc = 0.f;
            g = gr;
        }
        acc += bfLo((unsigned int)h[(size_t)r * 256 + c]);
    }
    atomicAdd(&psum[g * 256 + c], acc);
}

__device__ __forceinline__ int lower_bound_i(const int* __restrict__ a, int n, int v) {
    int lo = 0, hi = n;
    while (lo < hi) {
        int mid = (lo + hi) >> 1;
        if (a[mid] < v) lo = mid + 1; else hi = mid;
    }
    return lo;
}

__global__ __launch_bounds__(128) void k_head(const float* __restrict__ psum,
                                              const int* __restrict__ batch,
                                              const float* __restrict__ Wl,
                                              const float* __restrict__ bl,
                                              float* __restrict__ out, int n) {
    int tid = threadIdx.x;
    int g = tid >> 1, o = tid & 1;
    int s = lower_bound_i(batch, n, g);
    int e = lower_bound_i(batch, n, g + 1);
    float inv = 1.0f / (float)((e - s) > 1 ? (e - s) : 1);
    float sum = bl[o];
    for (int k = 0; k < 256; k++)
        sum = fmaf(psum[g * 256 + k] * inv, Wl[k * 2 + o], sum);
    out[g * 2 + o] = sum;
}

// ---------------- launch ----------------
extern "C" void kernel_launch(void* const* d_in, const int* in_sizes, int n_in,
                              void* d_out, int out_size, void* d_ws, size_t ws_size,
                              hipStream_t stream) {
    const float* x = (const float*)d_in[0];
    const int* ei = (const int*)d_in[1];
    const int* batch = (const int*)d_in[2];
    const float* W1 = (const float*)d_in[3];
    const float* b1 = (const float*)d_in[4];
    const float* W2 = (const float*)d_in[5];
    const float* b2 = (const float*)d_in[6];
    const float* V1 = (const float*)d_in[7];
    const float* c1 = (const float*)d_in[8];
    const float* V2 = (const float*)d_in[9];
    const float* c2 = (const float*)d_in[10];
    const float* Wl = (const float*)d_in[11];
    const float* bl = (const float*)d_in[12];
    float* out = (float*)d_out;

    const int* srcp = ei;
    const int* dstp = ei + N_EDGES;

    char* ws = (char*)d_ws;
    size_t off = 0;
    auto alloc = [&](size_t bytes) {
        size_t o = off;
        off = (off + bytes + 255) & ~(size_t)255;
        return o;
    };
    size_t o_deg = alloc(sizeof(int) * (N_NODES + 1));
    size_t o_rp = alloc(sizeof(int) * (N_NODES + 1));
    size_t o_wp = alloc(sizeof(int) * (N_NODES + 1));
    size_t o_bsum = alloc(sizeof(int) * SCAN_NB);
    size_t o_csr = alloc(sizeof(int) * N_EDGES);
    size_t o_B1 = alloc(sizeof(unsigned short) * (size_t)N_NODES * D_HID);
    size_t o_B2 = alloc(sizeof(unsigned short) * (size_t)N_NODES * D_HID);
    size_t o_pool = alloc(sizeof(float) * N_GRAPHS * D_HID);
    size_t o_wt1 = alloc(sizeof(unsigned short) * D_IN * D_HID);
    size_t o_wt2 = alloc(sizeof(unsigned short) * D_HID * D_HID);
    size_t o_wv1 = alloc(sizeof(unsigned short) * D_HID * D_HID);
    size_t o_wv2 = alloc(sizeof(unsigned short) * D_HID * D_HID);
    (void)ws_size;

    int* deg = (int*)(ws + o_deg);
    int* rp = (int*)(ws + o_rp);
    int* wp = (int*)(ws + o_wp);
    int* bsum = (int*)(ws + o_bsum);
    int* csr = (int*)(ws + o_csr);
    unsigned short* B1 = (unsigned short*)(ws + o_B1);
    unsigned short* B2 = (unsigned short*)(ws + o_B2);
    float* psum = (float*)(ws + o_pool);
    unsigned short* wt1 = (unsigned short*)(ws + o_wt1);
    unsigned short* wt2 = (unsigned short*)(ws + o_wt2);
    unsigned short* wv1 = (unsigned short*)(ws + o_wv1);
    unsigned short* wv2 = (unsigned short*)(ws + o_wv2);

    hipMemsetAsync(deg, 0, sizeof(int) * (N_NODES + 1), stream);
    hipMemsetAsync(psum, 0, sizeof(float) * N_GRAPHS * D_HID, stream);

    k_wt<<<D_IN, 256, 0, stream>>>(W1, wt1, D_IN);
    k_wt<<<D_HID, 256, 0, stream>>>(W2, wt2, D_HID);
    k_wt<<<D_HID, 256, 0, stream>>>(V1, wv1, D_HID);
    k_wt<<<D_HID, 256, 0, stream>>>(V2, wv2, D_HID);

    k_count<<<(N_EDGES + 255) / 256, 256, 0, stream>>>(dstp, deg, N_EDGES);
    k_scan1<<<SCAN_NB, 256, 0, stream>>>(deg, bsum, N_NODES);
    k_scan2<<<1, 256, 0, stream>>>(bsum, SCAN_NB);
    k_scan3<<<SCAN_NB, 256, 0, stream>>>(deg, bsum, rp, wp, N_NODES);
    k_scatter2<<<256, 256, 0, stream>>>(srcp, dstp, wp, csr, N_EDGES);

    // x -> bf16 (into B1)
    k_x2bf<<<(N_NODES * D_IN / 4 + 255) / 256, 256, 0, stream>>>(x, B1, N_NODES * D_IN / 4);

    dim3 ggrid((N_NODES + 63) / 64, 2);

    // layer 1: h0 = xb + agg(xb) -> B2; t1 = relu(h0@W1+b1) -> B1; h1 = relu(t1@W2+b2) -> B2
    k_agg96b<<<(N_NODES + 3) / 4, 256, 0, stream>>>(B1, rp, csr, B2, N_NODES);
    gemm_mfma<96, true, true><<<ggrid, 256, 0, stream>>>(B2, wt1, b1, B1, N_NODES);
    gemm_mfma<256, true, true><<<ggrid, 256, 0, stream>>>(B1, wt2, b2, B2, N_NODES);

    // layer 2: g2 = h1 + agg(h1) -> B1; t2 = relu(g2@V1+c1) -> B2; h2(bf16) = t2@V2+c2 -> B1
    k_agg256b<<<(N_NODES + 3) / 4, 256, 0, stream>>>(B2, rp, csr, B1, N_NODES);
    gemm_mfma<256, true, true><<<ggrid, 256, 0, stream>>>(B1, wv1, c1, B2, N_NODES);
    gemm_mfma<256, false, true><<<ggrid, 256, 0, stream>>>(B2, wv2, c2, B1, N_NODES);

    // pool + head
    k_pool_partial<<<(N_NODES + POOL_ROWS - 1) / POOL_ROWS, 256, 0, stream>>>(
        B1, batch, psum, N_NODES);
    k_head<<<1, 128, 0, stream>>>(psum, batch, Wl, bl, out, N_NODES);
}

// Round 17
// 321.858 us; speedup vs baseline: 1.2140x; 1.1534x over previous
//
// v17 — k_scatter2 with 2048 blocks (8 ranges x 256 chunks, 8 blocks/CU); v16's 256-block
// version was latency-starved at 9.8% occupancy. Everything else identical to v16.
#include <hip/hip_runtime.h>

#define N_NODES 50000
#define N_EDGES 800000
#define D_IN 96
#define D_HID 256
#define N_GRAPHS 64

#define SCAN_NB ((N_NODES + 255) / 256)

typedef __attribute__((ext_vector_type(8))) short bf16x8;
typedef __attribute__((ext_vector_type(4))) float f32x4;

__device__ __forceinline__ unsigned short f2bf(float f) {
    union { float f; unsigned int u; } v; v.f = f;
    unsigned int r = (v.u + 0x7FFFu + ((v.u >> 16) & 1u)) >> 16;  // RNE
    return (unsigned short)r;
}
__device__ __forceinline__ float bfLo(unsigned int u) {
    union { unsigned int u; float f; } v; v.u = u << 16; return v.f;
}
__device__ __forceinline__ float bfHi(unsigned int u) {
    union { unsigned int u; float f; } v; v.u = u & 0xFFFF0000u; return v.f;
}
__device__ __forceinline__ unsigned int packbf(float a, float b) {
    return (unsigned int)f2bf(a) | ((unsigned int)f2bf(b) << 16);
}

// ---------------- CSR build ----------------
__global__ void k_count(const int* __restrict__ dst, int* __restrict__ deg, int E) {
    int e = blockIdx.x * blockDim.x + threadIdx.x;
    if (e < E) atomicAdd(&deg[dst[e]], 1);
}

__global__ __launch_bounds__(256) void k_scan1(const int* __restrict__ deg,
                                               int* __restrict__ bsum, int n) {
    __shared__ int red[256];
    int tid = threadIdx.x;
    int i = blockIdx.x * 256 + tid;
    red[tid] = (i < n) ? deg[i] : 0;
    __syncthreads();
    for (int off = 128; off > 0; off >>= 1) {
        if (tid < off) red[tid] += red[tid + off];
        __syncthreads();
    }
    if (tid == 0) bsum[blockIdx.x] = red[0];
}

__global__ __launch_bounds__(256) void k_scan2(int* __restrict__ bsum, int nb) {
    __shared__ int s[256];
    int tid = threadIdx.x;
    int v = (tid < nb) ? bsum[tid] : 0;
    s[tid] = v;
    __syncthreads();
    for (int off = 1; off < 256; off <<= 1) {
        int t = (tid >= off) ? s[tid - off] : 0;
        __syncthreads();
        s[tid] += t;
        __syncthreads();
    }
    if (tid < nb) bsum[tid] = s[tid] - v;
}

__global__ __launch_bounds__(256) void k_scan3(const int* __restrict__ deg,
                                               const int* __restrict__ bsum,
                                               int* __restrict__ rp,
                                               int* __restrict__ wp, int n) {
    __shared__ int s[256];
    int tid = threadIdx.x;
    int i = blockIdx.x * 256 + tid;
    int v = (i < n) ? deg[i] : 0;
    s[tid] = v;
    __syncthreads();
    for (int off = 1; off < 256; off <<= 1) {
        int t = (tid >= off) ? s[tid - off] : 0;
        __syncthreads();
        s[tid] += t;
        __syncthreads();
    }
    if (i < n) {
        int excl = s[tid] - v + bsum[blockIdx.x];
        rp[i] = excl;
        wp[i] = excl;
    }
    if (blockIdx.x == 0 && tid == 0) rp[n] = N_EDGES;
}

// dst-range-partitioned scatter, 2048 blocks: range = bid&7 (XCD round-robin
// heuristic), chunk = bid>>3 (256 chunks of ~3125 edges). Each range's csr writes
// land in one compact ~400KB region -> stays in one L2. 8x coalesced dst re-read.
__global__ __launch_bounds__(256) void k_scatter2(const int* __restrict__ src,
                                                  const int* __restrict__ dst,
                                                  int* __restrict__ wp,
                                                  int* __restrict__ csr, int E) {
    int range = blockIdx.x & 7;
    int chunk = blockIdx.x >> 3;  // 0..255
    int lo = range * (N_NODES / 8);
    int hi = (range == 7) ? N_NODES : lo + (N_NODES / 8);
    int per = (E + 255) / 256;
    int s = chunk * per;
    int e = s + per;
    if (e > E) e = E;
    for (int i = s + threadIdx.x; i < e; i += 256) {
        int d = dst[i];
        if (d >= lo && d < hi) {
            int p = atomicAdd(&wp[d], 1);
            csr[p] = src[i];
        }
    }
}

// ---------------- x f32 -> bf16 ----------------
__global__ __launch_bounds__(256) void k_x2bf(const float* __restrict__ x,
                                              unsigned short* __restrict__ xb, int n4) {
    int i = blockIdx.x * 256 + threadIdx.x;
    if (i >= n4) return;
    float4 v = ((const float4*)x)[i];
    ((uint2*)xb)[i] = make_uint2(packbf(v.x, v.y), packbf(v.z, v.w));
}

#define ACCUM(acc, v)                                    \
    do {                                                 \
        acc[0] += bfLo((v).x); acc[1] += bfHi((v).x);    \
        acc[2] += bfLo((v).y); acc[3] += bfHi((v).y);    \
        acc[4] += bfLo((v).z); acc[5] += bfHi((v).z);    \
        acc[6] += bfLo((v).w); acc[7] += bfHi((v).w);    \
    } while (0)

// ---------------- aggregation (2x-unrolled, from v12) ----------------
__global__ __launch_bounds__(256) void k_agg96b(const unsigned short* __restrict__ xb,
                                                const int* __restrict__ rp,
                                                const int* __restrict__ csr,
                                                unsigned short* __restrict__ h0, int n) {
    int wid = blockIdx.x * 4 + (threadIdx.x >> 6);
    if (wid >= n) return;
    int lane = threadIdx.x & 63;
    int grp = lane / 12;
    int sub = lane % 12;
    int s = rp[wid], e = rp[wid + 1];
    const uint4* xp = (const uint4*)xb;
    float a[8] = {0.f, 0.f, 0.f, 0.f, 0.f, 0.f, 0.f, 0.f};
    float b[8] = {0.f, 0.f, 0.f, 0.f, 0.f, 0.f, 0.f, 0.f};
    if (lane < 48) {
        int j = s + grp;
        for (; j + 4 < e; j += 8) {
            int sc0 = csr[j];
            int sc1 = csr[j + 4];
            uint4 v0 = xp[(size_t)sc0 * 12 + sub];
            uint4 v1 = xp[(size_t)sc1 * 12 + sub];
            ACCUM(a, v0);
            ACCUM(b, v1);
        }
        if (j < e) {
            int sc0 = csr[j];
            uint4 v0 = xp[(size_t)sc0 * 12 + sub];
            ACCUM(a, v0);
        }
    }
#pragma unroll
    for (int i = 0; i < 8; i++) a[i] += b[i];
#pragma unroll
    for (int i = 0; i < 8; i++) a[i] += __shfl(a[i], lane + 24, 64);
#pragma unroll
    for (int i = 0; i < 8; i++) a[i] += __shfl(a[i], lane + 12, 64);
    if (lane < 12) {
        uint4 v = xp[(size_t)wid * 12 + sub];
        ACCUM(a, v);
        uint4 o;
        o.x = packbf(a[0], a[1]); o.y = packbf(a[2], a[3]);
        o.z = packbf(a[4], a[5]); o.w = packbf(a[6], a[7]);
        ((uint4*)h0)[(size_t)wid * 12 + sub] = o;
    }
}

__global__ __launch_bounds__(256) void k_agg256b(const unsigned short* __restrict__ h,
                                                 const int* __restrict__ rp,
                                                 const int* __restrict__ csr,
                                                 unsigned short* __restrict__ outb, int n) {
    int wid = blockIdx.x * 4 + (threadIdx.x >> 6);
    if (wid >= n) return;
    int lane = threadIdx.x & 63;
    int half = lane >> 5;
    int sub = lane & 31;
    int s = rp[wid], e = rp[wid + 1];
    const uint4* hp = (const uint4*)h;
    float a[8] = {0.f, 0.f, 0.f, 0.f, 0.f, 0.f, 0.f, 0.f};
    float b[8] = {0.f, 0.f, 0.f, 0.f, 0.f, 0.f, 0.f, 0.f};
    int j = s + half;
    for (; j + 2 < e; j += 4) {
        int sc0 = csr[j];
        int sc1 = csr[j + 2];
        uint4 v0 = hp[(size_t)sc0 * 32 + sub];
        uint4 v1 = hp[(size_t)sc1 * 32 + sub];
        ACCUM(a, v0);
        ACCUM(b, v1);
    }
    if (j < e) {
        int sc0 = csr[j];
        uint4 v0 = hp[(size_t)sc0 * 32 + sub];
        ACCUM(a, v0);
    }
#pragma unroll
    for (int i = 0; i < 8; i++) a[i] += b[i];
#pragma unroll
    for (int i = 0; i < 8; i++) a[i] += __shfl(a[i], sub + 32, 64);
    if (half == 0) {
        uint4 v = hp[(size_t)wid * 32 + sub];
        ACCUM(a, v);
        uint4 o;
        o.x = packbf(a[0], a[1]); o.y = packbf(a[2], a[3]);
        o.z = packbf(a[4], a[5]); o.w = packbf(a[6], a[7]);
        ((uint4*)outb)[(size_t)wid * 32 + sub] = o;
    }
}

// ---------------- weight transpose + bf16: W[K][256] -> Wt[256][K] ----------------
__global__ __launch_bounds__(256) void k_wt(const float* __restrict__ W,
                                            unsigned short* __restrict__ Wt, int K) {
    int idx = blockIdx.x * 256 + threadIdx.x;
    if (idx >= K * 256) return;
    int k = idx >> 8;
    int n = idx & 255;
    Wt[(size_t)n * K + k] = f2bf(W[idx]);
}

// ---------------- MFMA bf16 GEMM (v12's proven version) ----------------
template <int K, bool RELU, bool OUTBF>
__global__ __launch_bounds__(256) void gemm_mfma(const unsigned short* __restrict__ A,
                                                 const unsigned short* __restrict__ Wt,
                                                 const float* __restrict__ bias,
                                                 void* __restrict__ Cv, int M) {
    constexpr int BM = 64, BN = 128, BK = 64;
    __shared__ unsigned short As[BM][BK + 8];
    __shared__ unsigned short Bs[BN][BK + 8];
    const int tid = threadIdx.x;
    const int lane = tid & 63;
    const int wid = tid >> 6;
    const int wm = wid >> 1;
    const int wn = wid & 1;
    const int row0 = blockIdx.x * BM;
    const int col0 = blockIdx.y * BN;

    f32x4 acc[2][4];
#pragma unroll
    for (int f = 0; f < 2; f++)
#pragma unroll
        for (int g = 0; g < 4; g++) acc[f][g] = (f32x4){0.f, 0.f, 0.f, 0.f};

    for (int kt = 0; kt < K; kt += BK) {
        __syncthreads();
        {
            int m = tid >> 2;
            int kc = (tid & 3) * 16;
            int gr = row0 + m;
            uint4 w0 = make_uint4(0u, 0u, 0u, 0u), w1 = w0;
            int k = kt + kc;
            if (gr < M && k < K) {
                w0 = *(const uint4*)&A[(size_t)gr * K + k];
                if (k + 8 < K) w1 = *(const uint4*)&A[(size_t)gr * K + k + 8];
            }
            uint4* dst = (uint4*)&As[m][kc];
            dst[0] = w0; dst[1] = w1;
        }
        {
            int n = tid >> 1;
            int kc = (tid & 1) * 32;
            uint4 w[4];
#pragma unroll
            for (int i = 0; i < 4; i++) {
                int k = kt + kc + i * 8;
                if (k < K)
                    w[i] = *(const uint4*)&Wt[(size_t)(col0 + n) * K + k];
                else
                    w[i] = make_uint4(0u, 0u, 0u, 0u);
            }
            uint4* dst = (uint4*)&Bs[n][kc];
#pragma unroll
            for (int i = 0; i < 4; i++) dst[i] = w[i];
        }
        __syncthreads();
#pragma unroll
        for (int ks = 0; ks < 2; ks++) {
            int ko = ks * 32 + (lane >> 4) * 8;
            bf16x8 af[2], bfr[4];
#pragma unroll
            for (int f = 0; f < 2; f++)
                af[f] = *(const bf16x8*)&As[wm * 32 + f * 16 + (lane & 15)][ko];
#pragma unroll
            for (int g = 0; g < 4; g++)
                bfr[g] = *(const bf16x8*)&Bs[wn * 64 + g * 16 + (lane & 15)][ko];
#pragma unroll
            for (int f = 0; f < 2; f++)
#pragma unroll
                for (int g = 0; g < 4; g++)
                    acc[f][g] = __builtin_amdgcn_mfma_f32_16x16x32_bf16(
                        af[f], bfr[g], acc[f][g], 0, 0, 0);
        }
    }

#pragma unroll
    for (int g = 0; g < 4; g++) {
        int n = col0 + wn * 64 + g * 16 + (lane & 15);
        float bb = bias[n];
#pragma unroll
        for (int f = 0; f < 2; f++) {
#pragma unroll
            for (int r = 0; r < 4; r++) {
                int m = row0 + wm * 32 + f * 16 + (lane >> 4) * 4 + r;
                if (m < M) {
                    float v = acc[f][g][r] + bb;
                    if (RELU) v = fmaxf(v, 0.f);
                    if (OUTBF)
                        ((unsigned short*)Cv)[(size_t)m * 256 + n] = f2bf(v);
                    else
                        ((float*)Cv)[(size_t)m * 256 + n] = v;
                }
            }
        }
    }
}

// ---------------- pooling (two-stage, bf16 input) ----------------
#define POOL_ROWS 64
__global__ __launch_bounds__(256) void k_pool_partial(const unsigned short* __restrict__ h,
                                                      const int* __restrict__ batch,
                                                      float* __restrict__ psum, int n) {
    int r0 = blockIdx.x * POOL_ROWS;
    int r1 = r0 + POOL_ROWS;
    if (r1 > n) r1 = n;
    if (r0 >= r1) return;
    int c = threadIdx.x;
    float acc = 0.f;
    int g = batch[r0];
    for (int r = r0; r < r1; r++) {
        int gr = batch[r];
        if (gr != g) {
            atomicAdd(&psum[g * 256 + c], acc);
            acc = 0.f;
            g = gr;
        }
        acc += bfLo((unsigned int)h[(size_t)r * 256 + c]);
    }
    atomicAdd(&psum[g * 256 + c], acc);
}

__device__ __forceinline__ int lower_bound_i(const int* __restrict__ a, int n, int v) {
    int lo = 0, hi = n;
    while (lo < hi) {
        int mid = (lo + hi) >> 1;
        if (a[mid] < v) lo = mid + 1; else hi = mid;
    }
    return lo;
}

__global__ __launch_bounds__(128) void k_head(const float* __restrict__ psum,
                                              const int* __restrict__ batch,
                                              const float* __restrict__ Wl,
                                              const float* __restrict__ bl,
                                              float* __restrict__ out, int n) {
    int tid = threadIdx.x;
    int g = tid >> 1, o = tid & 1;
    int s = lower_bound_i(batch, n, g);
    int e = lower_bound_i(batch, n, g + 1);
    float inv = 1.0f / (float)((e - s) > 1 ? (e - s) : 1);
    float sum = bl[o];
    for (int k = 0; k < 256; k++)
        sum = fmaf(psum[g * 256 + k] * inv, Wl[k * 2 + o], sum);
    out[g * 2 + o] = sum;
}

// ---------------- launch ----------------
extern "C" void kernel_launch(void* const* d_in, const int* in_sizes, int n_in,
                              void* d_out, int out_size, void* d_ws, size_t ws_size,
                              hipStream_t stream) {
    const float* x = (const float*)d_in[0];
    const int* ei = (const int*)d_in[1];
    const int* batch = (const int*)d_in[2];
    const float* W1 = (const float*)d_in[3];
    const float* b1 = (const float*)d_in[4];
    const float* W2 = (const float*)d_in[5];
    const float* b2 = (const float*)d_in[6];
    const float* V1 = (const float*)d_in[7];
    const float* c1 = (const float*)d_in[8];
    const float* V2 = (const float*)d_in[9];
    const float* c2 = (const float*)d_in[10];
    const float* Wl = (const float*)d_in[11];
    const float* bl = (const float*)d_in[12];
    float* out = (float*)d_out;

    const int* srcp = ei;
    const int* dstp = ei + N_EDGES;

    char* ws = (char*)d_ws;
    size_t off = 0;
    auto alloc = [&](size_t bytes) {
        size_t o = off;
        off = (off + bytes + 255) & ~(size_t)255;
        return o;
    };
    size_t o_deg = alloc(sizeof(int) * (N_NODES + 1));
    size_t o_rp = alloc(sizeof(int) * (N_NODES + 1));
    size_t o_wp = alloc(sizeof(int) * (N_NODES + 1));
    size_t o_bsum = alloc(sizeof(int) * SCAN_NB);
    size_t o_csr = alloc(sizeof(int) * N_EDGES);
    size_t o_B1 = alloc(sizeof(unsigned short) * (size_t)N_NODES * D_HID);
    size_t o_B2 = alloc(sizeof(unsigned short) * (size_t)N_NODES * D_HID);
    size_t o_pool = alloc(sizeof(float) * N_GRAPHS * D_HID);
    size_t o_wt1 = alloc(sizeof(unsigned short) * D_IN * D_HID);
    size_t o_wt2 = alloc(sizeof(unsigned short) * D_HID * D_HID);
    size_t o_wv1 = alloc(sizeof(unsigned short) * D_HID * D_HID);
    size_t o_wv2 = alloc(sizeof(unsigned short) * D_HID * D_HID);
    (void)ws_size;

    int* deg = (int*)(ws + o_deg);
    int* rp = (int*)(ws + o_rp);
    int* wp = (int*)(ws + o_wp);
    int* bsum = (int*)(ws + o_bsum);
    int* csr = (int*)(ws + o_csr);
    unsigned short* B1 = (unsigned short*)(ws + o_B1);
    unsigned short* B2 = (unsigned short*)(ws + o_B2);
    float* psum = (float*)(ws + o_pool);
    unsigned short* wt1 = (unsigned short*)(ws + o_wt1);
    unsigned short* wt2 = (unsigned short*)(ws + o_wt2);
    unsigned short* wv1 = (unsigned short*)(ws + o_wv1);
    unsigned short* wv2 = (unsigned short*)(ws + o_wv2);

    hipMemsetAsync(deg, 0, sizeof(int) * (N_NODES + 1), stream);
    hipMemsetAsync(psum, 0, sizeof(float) * N_GRAPHS * D_HID, stream);

    k_wt<<<D_IN, 256, 0, stream>>>(W1, wt1, D_IN);
    k_wt<<<D_HID, 256, 0, stream>>>(W2, wt2, D_HID);
    k_wt<<<D_HID, 256, 0, stream>>>(V1, wv1, D_HID);
    k_wt<<<D_HID, 256, 0, stream>>>(V2, wv2, D_HID);

    k_count<<<(N_EDGES + 255) / 256, 256, 0, stream>>>(dstp, deg, N_EDGES);
    k_scan1<<<SCAN_NB, 256, 0, stream>>>(deg, bsum, N_NODES);
    k_scan2<<<1, 256, 0, stream>>>(bsum, SCAN_NB);
    k_scan3<<<SCAN_NB, 256, 0, stream>>>(deg, bsum, rp, wp, N_NODES);
    k_scatter2<<<2048, 256, 0, stream>>>(srcp, dstp, wp, csr, N_EDGES);

    // x -> bf16 (into B1)
    k_x2bf<<<(N_NODES * D_IN / 4 + 255) / 256, 256, 0, stream>>>(x, B1, N_NODES * D_IN / 4);

    dim3 ggrid((N_NODES + 63) / 64, 2);

    // layer 1: h0 = xb + agg(xb) -> B2; t1 = relu(h0@W1+b1) -> B1; h1 = relu(t1@W2+b2) -> B2
    k_agg96b<<<(N_NODES + 3) / 4, 256, 0, stream>>>(B1, rp, csr, B2, N_NODES);
    gemm_mfma<96, true, true><<<ggrid, 256, 0, stream>>>(B2, wt1, b1, B1, N_NODES);
    gemm_mfma<256, true, true><<<ggrid, 256, 0, stream>>>(B1, wt2, b2, B2, N_NODES);

    // layer 2: g2 = h1 + agg(h1) -> B1; t2 = relu(g2@V1+c1) -> B2; h2(bf16) = t2@V2+c2 -> B1
    k_agg256b<<<(N_NODES + 3) / 4, 256, 0, stream>>>(B2, rp, csr, B1, N_NODES);
    gemm_mfma<256, true, true><<<ggrid, 256, 0, stream>>>(B1, wv1, c1, B2, N_NODES);
    gemm_mfma<256, false, true><<<ggrid, 256, 0, stream>>>(B2, wv2, c2, B1, N_NODES);

    // pool + head
    k_pool_partial<<<(N_NODES + POOL_ROWS - 1) / POOL_ROWS, 256, 0, stream>>>(
        B1, batch, psum, N_NODES);
    k_head<<<1, 128, 0, stream>>>(psum, batch, Wl, bl, out, N_NODES);
}

// Round 19
// 315.358 us; speedup vs baseline: 1.2390x; 1.0206x over previous
//
// v19 — identical to v18 (gemm XCD swizzle + merged k_wt_all); resubmission after
// UnresponsiveContainer infra failure.
#include <hip/hip_runtime.h>

#define N_NODES 50000
#define N_EDGES 800000
#define D_IN 96
#define D_HID 256
#define N_GRAPHS 64

#define SCAN_NB ((N_NODES + 255) / 256)

typedef __attribute__((ext_vector_type(8))) short bf16x8;
typedef __attribute__((ext_vector_type(4))) float f32x4;

__device__ __forceinline__ unsigned short f2bf(float f) {
    union { float f; unsigned int u; } v; v.f = f;
    unsigned int r = (v.u + 0x7FFFu + ((v.u >> 16) & 1u)) >> 16;  // RNE
    return (unsigned short)r;
}
__device__ __forceinline__ float bfLo(unsigned int u) {
    union { unsigned int u; float f; } v; v.u = u << 16; return v.f;
}
__device__ __forceinline__ float bfHi(unsigned int u) {
    union { unsigned int u; float f; } v; v.u = u & 0xFFFF0000u; return v.f;
}
__device__ __forceinline__ unsigned int packbf(float a, float b) {
    return (unsigned int)f2bf(a) | ((unsigned int)f2bf(b) << 16);
}

// ---------------- CSR build ----------------
__global__ void k_count(const int* __restrict__ dst, int* __restrict__ deg, int E) {
    int e = blockIdx.x * blockDim.x + threadIdx.x;
    if (e < E) atomicAdd(&deg[dst[e]], 1);
}

__global__ __launch_bounds__(256) void k_scan1(const int* __restrict__ deg,
                                               int* __restrict__ bsum, int n) {
    __shared__ int red[256];
    int tid = threadIdx.x;
    int i = blockIdx.x * 256 + tid;
    red[tid] = (i < n) ? deg[i] : 0;
    __syncthreads();
    for (int off = 128; off > 0; off >>= 1) {
        if (tid < off) red[tid] += red[tid + off];
        __syncthreads();
    }
    if (tid == 0) bsum[blockIdx.x] = red[0];
}

__global__ __launch_bounds__(256) void k_scan2(int* __restrict__ bsum, int nb) {
    __shared__ int s[256];
    int tid = threadIdx.x;
    int v = (tid < nb) ? bsum[tid] : 0;
    s[tid] = v;
    __syncthreads();
    for (int off = 1; off < 256; off <<= 1) {
        int t = (tid >= off) ? s[tid - off] : 0;
        __syncthreads();
        s[tid] += t;
        __syncthreads();
    }
    if (tid < nb) bsum[tid] = s[tid] - v;
}

__global__ __launch_bounds__(256) void k_scan3(const int* __restrict__ deg,
                                               const int* __restrict__ bsum,
                                               int* __restrict__ rp,
                                               int* __restrict__ wp, int n) {
    __shared__ int s[256];
    int tid = threadIdx.x;
    int i = blockIdx.x * 256 + tid;
    int v = (i < n) ? deg[i] : 0;
    s[tid] = v;
    __syncthreads();
    for (int off = 1; off < 256; off <<= 1) {
        int t = (tid >= off) ? s[tid - off] : 0;
        __syncthreads();
        s[tid] += t;
        __syncthreads();
    }
    if (i < n) {
        int excl = s[tid] - v + bsum[blockIdx.x];
        rp[i] = excl;
        wp[i] = excl;
    }
    if (blockIdx.x == 0 && tid == 0) rp[n] = N_EDGES;
}

// dst-range-partitioned scatter, 2048 blocks (8 ranges x 256 chunks).
__global__ __launch_bounds__(256) void k_scatter2(const int* __restrict__ src,
                                                  const int* __restrict__ dst,
                                                  int* __restrict__ wp,
                                                  int* __restrict__ csr, int E) {
    int range = blockIdx.x & 7;
    int chunk = blockIdx.x >> 3;  // 0..255
    int lo = range * (N_NODES / 8);
    int hi = (range == 7) ? N_NODES : lo + (N_NODES / 8);
    int per = (E + 255) / 256;
    int s = chunk * per;
    int e = s + per;
    if (e > E) e = E;
    for (int i = s + threadIdx.x; i < e; i += 256) {
        int d = dst[i];
        if (d >= lo && d < hi) {
            int p = atomicAdd(&wp[d], 1);
            csr[p] = src[i];
        }
    }
}

// ---------------- x f32 -> bf16 ----------------
__global__ __launch_bounds__(256) void k_x2bf(const float* __restrict__ x,
                                              unsigned short* __restrict__ xb, int n4) {
    int i = blockIdx.x * 256 + threadIdx.x;
    if (i >= n4) return;
    float4 v = ((const float4*)x)[i];
    ((uint2*)xb)[i] = make_uint2(packbf(v.x, v.y), packbf(v.z, v.w));
}

#define ACCUM(acc, v)                                    \
    do {                                                 \
        acc[0] += bfLo((v).x); acc[1] += bfHi((v).x);    \
        acc[2] += bfLo((v).y); acc[3] += bfHi((v).y);    \
        acc[4] += bfLo((v).z); acc[5] += bfHi((v).z);    \
        acc[6] += bfLo((v).w); acc[7] += bfHi((v).w);    \
    } while (0)

// ---------------- aggregation (2x-unrolled, from v12) ----------------
__global__ __launch_bounds__(256) void k_agg96b(const unsigned short* __restrict__ xb,
                                                const int* __restrict__ rp,
                                                const int* __restrict__ csr,
                                                unsigned short* __restrict__ h0, int n) {
    int wid = blockIdx.x * 4 + (threadIdx.x >> 6);
    if (wid >= n) return;
    int lane = threadIdx.x & 63;
    int grp = lane / 12;
    int sub = lane % 12;
    int s = rp[wid], e = rp[wid + 1];
    const uint4* xp = (const uint4*)xb;
    float a[8] = {0.f, 0.f, 0.f, 0.f, 0.f, 0.f, 0.f, 0.f};
    float b[8] = {0.f, 0.f, 0.f, 0.f, 0.f, 0.f, 0.f, 0.f};
    if (lane < 48) {
        int j = s + grp;
        for (; j + 4 < e; j += 8) {
            int sc0 = csr[j];
            int sc1 = csr[j + 4];
            uint4 v0 = xp[(size_t)sc0 * 12 + sub];
            uint4 v1 = xp[(size_t)sc1 * 12 + sub];
            ACCUM(a, v0);
            ACCUM(b, v1);
        }
        if (j < e) {
            int sc0 = csr[j];
            uint4 v0 = xp[(size_t)sc0 * 12 + sub];
            ACCUM(a, v0);
        }
    }
#pragma unroll
    for (int i = 0; i < 8; i++) a[i] += b[i];
#pragma unroll
    for (int i = 0; i < 8; i++) a[i] += __shfl(a[i], lane + 24, 64);
#pragma unroll
    for (int i = 0; i < 8; i++) a[i] += __shfl(a[i], lane + 12, 64);
    if (lane < 12) {
        uint4 v = xp[(size_t)wid * 12 + sub];
        ACCUM(a, v);
        uint4 o;
        o.x = packbf(a[0], a[1]); o.y = packbf(a[2], a[3]);
        o.z = packbf(a[4], a[5]); o.w = packbf(a[6], a[7]);
        ((uint4*)h0)[(size_t)wid * 12 + sub] = o;
    }
}

__global__ __launch_bounds__(256) void k_agg256b(const unsigned short* __restrict__ h,
                                                 const int* __restrict__ rp,
                                                 const int* __restrict__ csr,
                                                 unsigned short* __restrict__ outb, int n) {
    int wid = blockIdx.x * 4 + (threadIdx.x >> 6);
    if (wid >= n) return;
    int lane = threadIdx.x & 63;
    int half = lane >> 5;
    int sub = lane & 31;
    int s = rp[wid], e = rp[wid + 1];
    const uint4* hp = (const uint4*)h;
    float a[8] = {0.f, 0.f, 0.f, 0.f, 0.f, 0.f, 0.f, 0.f};
    float b[8] = {0.f, 0.f, 0.f, 0.f, 0.f, 0.f, 0.f, 0.f};
    int j = s + half;
    for (; j + 2 < e; j += 4) {
        int sc0 = csr[j];
        int sc1 = csr[j + 2];
        uint4 v0 = hp[(size_t)sc0 * 32 + sub];
        uint4 v1 = hp[(size_t)sc1 * 32 + sub];
        ACCUM(a, v0);
        ACCUM(b, v1);
    }
    if (j < e) {
        int sc0 = csr[j];
        uint4 v0 = hp[(size_t)sc0 * 32 + sub];
        ACCUM(a, v0);
    }
#pragma unroll
    for (int i = 0; i < 8; i++) a[i] += b[i];
#pragma unroll
    for (int i = 0; i < 8; i++) a[i] += __shfl(a[i], sub + 32, 64);
    if (half == 0) {
        uint4 v = hp[(size_t)wid * 32 + sub];
        ACCUM(a, v);
        uint4 o;
        o.x = packbf(a[0], a[1]); o.y = packbf(a[2], a[3]);
        o.z = packbf(a[4], a[5]); o.w = packbf(a[6], a[7]);
        ((uint4*)outb)[(size_t)wid * 32 + sub] = o;
    }
}

// ---------------- weight transpose + bf16 (all 4 matrices, one dispatch) ----------------
__global__ __launch_bounds__(256) void k_wt_all(const float* __restrict__ W1,
                                                const float* __restrict__ W2,
                                                const float* __restrict__ V1,
                                                const float* __restrict__ V2,
                                                unsigned short* __restrict__ wt1,
                                                unsigned short* __restrict__ wt2,
                                                unsigned short* __restrict__ wv1,
                                                unsigned short* __restrict__ wv2) {
    int idx = blockIdx.x * 256 + threadIdx.x;
    if (idx < D_IN * 256) {
        int k = idx >> 8, n = idx & 255;
        wt1[(size_t)n * D_IN + k] = f2bf(W1[idx]);
        return;
    }
    idx -= D_IN * 256;
    int mat = idx >> 16;        // 0..2 (65536 elements each)
    int r = idx & 65535;
    int k = r >> 8, n = r & 255;
    const float* Ws = (mat == 0) ? W2 : (mat == 1) ? V1 : V2;
    unsigned short* Ds = (mat == 0) ? wt2 : (mat == 1) ? wv1 : wv2;
    Ds[(size_t)n * 256 + k] = f2bf(Ws[r]);
}

// ---------------- MFMA bf16 GEMM (v12 inner loops; XCD-aware block swizzle) ----------------
template <int K, bool RELU, bool OUTBF>
__global__ __launch_bounds__(256) void gemm_mfma(const unsigned short* __restrict__ A,
                                                 const unsigned short* __restrict__ Wt,
                                                 const float* __restrict__ bias,
                                                 void* __restrict__ Cv, int M) {
    constexpr int BM = 64, BN = 128, BK = 64;
    __shared__ unsigned short As[BM][BK + 8];
    __shared__ unsigned short Bs[BN][BK + 8];
    const int tid = threadIdx.x;
    const int lane = tid & 63;
    const int wid = tid >> 6;
    const int wm = wid >> 1;
    const int wn = wid & 1;

    // XCD-aware swizzle of (row-block, col-half)
    const int nrb = (M + 63) >> 6;
    const int nfull2 = ((nrb >> 3) << 3) * 2;
    int bid = blockIdx.x;
    int rblk, halfc;
    if (bid < nfull2) {
        int g = bid >> 4, w = bid & 15;
        halfc = w >> 3;
        rblk = g * 8 + (w & 7);
    } else {
        int idx = bid - nfull2;
        int rem = nrb - (nfull2 >> 1);
        rblk = (nfull2 >> 1) + (idx % rem);
        halfc = idx / rem;
    }
    const int row0 = rblk * BM;
    const int col0 = halfc * BN;

    f32x4 acc[2][4];
#pragma unroll
    for (int f = 0; f < 2; f++)
#pragma unroll
        for (int g = 0; g < 4; g++) acc[f][g] = (f32x4){0.f, 0.f, 0.f, 0.f};

    for (int kt = 0; kt < K; kt += BK) {
        __syncthreads();
        {
            int m = tid >> 2;
            int kc = (tid & 3) * 16;
            int gr = row0 + m;
            uint4 w0 = make_uint4(0u, 0u, 0u, 0u), w1 = w0;
            int k = kt + kc;
            if (gr < M && k < K) {
                w0 = *(const uint4*)&A[(size_t)gr * K + k];
                if (k + 8 < K) w1 = *(const uint4*)&A[(size_t)gr * K + k + 8];
            }
            uint4* dst = (uint4*)&As[m][kc];
            dst[0] = w0; dst[1] = w1;
        }
        {
            int n = tid >> 1;
            int kc = (tid & 1) * 32;
            uint4 w[4];
#pragma unroll
            for (int i = 0; i < 4; i++) {
                int k = kt + kc + i * 8;
                if (k < K)
                    w[i] = *(const uint4*)&Wt[(size_t)(col0 + n) * K + k];
                else
                    w[i] = make_uint4(0u, 0u, 0u, 0u);
            }
            uint4* dst = (uint4*)&Bs[n][kc];
#pragma unroll
            for (int i = 0; i < 4; i++) dst[i] = w[i];
        }
        __syncthreads();
#pragma unroll
        for (int ks = 0; ks < 2; ks++) {
            int ko = ks * 32 + (lane >> 4) * 8;
            bf16x8 af[2], bfr[4];
#pragma unroll
            for (int f = 0; f < 2; f++)
                af[f] = *(const bf16x8*)&As[wm * 32 + f * 16 + (lane & 15)][ko];
#pragma unroll
            for (int g = 0; g < 4; g++)
                bfr[g] = *(const bf16x8*)&Bs[wn * 64 + g * 16 + (lane & 15)][ko];
#pragma unroll
            for (int f = 0; f < 2; f++)
#pragma unroll
                for (int g = 0; g < 4; g++)
                    acc[f][g] = __builtin_amdgcn_mfma_f32_16x16x32_bf16(
                        af[f], bfr[g], acc[f][g], 0, 0, 0);
        }
    }

#pragma unroll
    for (int g = 0; g < 4; g++) {
        int n = col0 + wn * 64 + g * 16 + (lane & 15);
        float bb = bias[n];
#pragma unroll
        for (int f = 0; f < 2; f++) {
#pragma unroll
            for (int r = 0; r < 4; r++) {
                int m = row0 + wm * 32 + f * 16 + (lane >> 4) * 4 + r;
                if (m < M) {
                    float v = acc[f][g][r] + bb;
                    if (RELU) v = fmaxf(v, 0.f);
                    if (OUTBF)
                        ((unsigned short*)Cv)[(size_t)m * 256 + n] = f2bf(v);
                    else
                        ((float*)Cv)[(size_t)m * 256 + n] = v;
                }
            }
        }
    }
}

// ---------------- pooling (two-stage, bf16 input) ----------------
#define POOL_ROWS 64
__global__ __launch_bounds__(256) void k_pool_partial(const unsigned short* __restrict__ h,
                                                      const int* __restrict__ batch,
                                                      float* __restrict__ psum, int n) {
    int r0 = blockIdx.x * POOL_ROWS;
    int r1 = r0 + POOL_ROWS;
    if (r1 > n) r1 = n;
    if (r0 >= r1) return;
    int c = threadIdx.x;
    float acc = 0.f;
    int g = batch[r0];
    for (int r = r0; r < r1; r++) {
        int gr = batch[r];
        if (gr != g) {
            atomicAdd(&psum[g * 256 + c], acc);
            acc = 0.f;
            g = gr;
        }
        acc += bfLo((unsigned int)h[(size_t)r * 256 + c]);
    }
    atomicAdd(&psum[g * 256 + c], acc);
}

__device__ __forceinline__ int lower_bound_i(const int* __restrict__ a, int n, int v) {
    int lo = 0, hi = n;
    while (lo < hi) {
        int mid = (lo + hi) >> 1;
        if (a[mid] < v) lo = mid + 1; else hi = mid;
    }
    return lo;
}

__global__ __launch_bounds__(128) void k_head(const float* __restrict__ psum,
                                              const int* __restrict__ batch,
                                              const float* __restrict__ Wl,
                                              const float* __restrict__ bl,
                                              float* __restrict__ out, int n) {
    int tid = threadIdx.x;
    int g = tid >> 1, o = tid & 1;
    int s = lower_bound_i(batch, n, g);
    int e = lower_bound_i(batch, n, g + 1);
    float inv = 1.0f / (float)((e - s) > 1 ? (e - s) : 1);
    float sum = bl[o];
    for (int k = 0; k < 256; k++)
        sum = fmaf(psum[g * 256 + k] * inv, Wl[k * 2 + o], sum);
    out[g * 2 + o] = sum;
}

// ---------------- launch ----------------
extern "C" void kernel_launch(void* const* d_in, const int* in_sizes, int n_in,
                              void* d_out, int out_size, void* d_ws, size_t ws_size,
                              hipStream_t stream) {
    const float* x = (const float*)d_in[0];
    const int* ei = (const int*)d_in[1];
    const int* batch = (const int*)d_in[2];
    const float* W1 = (const float*)d_in[3];
    const float* b1 = (const float*)d_in[4];
    const float* W2 = (const float*)d_in[5];
    const float* b2 = (const float*)d_in[6];
    const float* V1 = (const float*)d_in[7];
    const float* c1 = (const float*)d_in[8];
    const float* V2 = (const float*)d_in[9];
    const float* c2 = (const float*)d_in[10];
    const float* Wl = (const float*)d_in[11];
    const float* bl = (const float*)d_in[12];
    float* out = (float*)d_out;

    const int* srcp = ei;
    const int* dstp = ei + N_EDGES;

    char* ws = (char*)d_ws;
    size_t off = 0;
    auto alloc = [&](size_t bytes) {
        size_t o = off;
        off = (off + bytes + 255) & ~(size_t)255;
        return o;
    };
    size_t o_deg = alloc(sizeof(int) * (N_NODES + 1));
    size_t o_rp = alloc(sizeof(int) * (N_NODES + 1));
    size_t o_wp = alloc(sizeof(int) * (N_NODES + 1));
    size_t o_bsum = alloc(sizeof(int) * SCAN_NB);
    size_t o_csr = alloc(sizeof(int) * N_EDGES);
    size_t o_B1 = alloc(sizeof(unsigned short) * (size_t)N_NODES * D_HID);
    size_t o_B2 = alloc(sizeof(unsigned short) * (size_t)N_NODES * D_HID);
    size_t o_pool = alloc(sizeof(float) * N_GRAPHS * D_HID);
    size_t o_wt1 = alloc(sizeof(unsigned short) * D_IN * D_HID);
    size_t o_wt2 = alloc(sizeof(unsigned short) * D_HID * D_HID);
    size_t o_wv1 = alloc(sizeof(unsigned short) * D_HID * D_HID);
    size_t o_wv2 = alloc(sizeof(unsigned short) * D_HID * D_HID);
    (void)ws_size;

    int* deg = (int*)(ws + o_deg);
    int* rp = (int*)(ws + o_rp);
    int* wp = (int*)(ws + o_wp);
    int* bsum = (int*)(ws + o_bsum);
    int* csr = (int*)(ws + o_csr);
    unsigned short* B1 = (unsigned short*)(ws + o_B1);
    unsigned short* B2 = (unsigned short*)(ws + o_B2);
    float* psum = (float*)(ws + o_pool);
    unsigned short* wt1 = (unsigned short*)(ws + o_wt1);
    unsigned short* wt2 = (unsigned short*)(ws + o_wt2);
    unsigned short* wv1 = (unsigned short*)(ws + o_wv1);
    unsigned short* wv2 = (unsigned short*)(ws + o_wv2);

    hipMemsetAsync(deg, 0, sizeof(int) * (N_NODES + 1), stream);
    hipMemsetAsync(psum, 0, sizeof(float) * N_GRAPHS * D_HID, stream);

    // all weight transposes in one dispatch
    k_wt_all<<<(D_IN * 256 + 3 * 65536 + 255) / 256, 256, 0, stream>>>(
        W1, W2, V1, V2, wt1, wt2, wv1, wv2);

    k_count<<<(N_EDGES + 255) / 256, 256, 0, stream>>>(dstp, deg, N_EDGES);
    k_scan1<<<SCAN_NB, 256, 0, stream>>>(deg, bsum, N_NODES);
    k_scan2<<<1, 256, 0, stream>>>(bsum, SCAN_NB);
    k_scan3<<<SCAN_NB, 256, 0, stream>>>(deg, bsum, rp, wp, N_NODES);
    k_scatter2<<<2048, 256, 0, stream>>>(srcp, dstp, wp, csr, N_EDGES);

    // x -> bf16 (into B1)
    k_x2bf<<<(N_NODES * D_IN / 4 + 255) / 256, 256, 0, stream>>>(x, B1, N_NODES * D_IN / 4);

    int nrb = (N_NODES + 63) / 64;
    int ggrid = nrb * 2;

    // layer 1: h0 = xb + agg(xb) -> B2; t1 = relu(h0@W1+b1) -> B1; h1 = relu(t1@W2+b2) -> B2
    k_agg96b<<<(N_NODES + 3) / 4, 256, 0, stream>>>(B1, rp, csr, B2, N_NODES);
    gemm_mfma<96, true, true><<<ggrid, 256, 0, stream>>>(B2, wt1, b1, B1, N_NODES);
    gemm_mfma<256, true, true><<<ggrid, 256, 0, stream>>>(B1, wt2, b2, B2, N_NODES);

    // layer 2: g2 = h1 + agg(h1) -> B1; t2 = relu(g2@V1+c1) -> B2; h2(bf16) = t2@V2+c2 -> B1
    k_agg256b<<<(N_NODES + 3) / 4, 256, 0, stream>>>(B2, rp, csr, B1, N_NODES);
    gemm_mfma<256, true, true><<<ggrid, 256, 0, stream>>>(B1, wv1, c1, B2, N_NODES);
    gemm_mfma<256, false, true><<<ggrid, 256, 0, stream>>>(B2, wv2, c2, B1, N_NODES);

    // pool + head
    k_pool_partial<<<(N_NODES + POOL_ROWS - 1) / POOL_ROWS, 256, 0, stream>>>(
        B1, batch, psum, N_NODES);
    k_head<<<1, 128, 0, stream>>>(psum, batch, Wl, bl, out, N_NODES);
}